// Round 4
// baseline (76.351 us; speedup 1.0000x reference)
//
#include <hip/hip_runtime.h>

#define NB 8
#define SL 128
#define HD 768

// Kernel 1: one block per (b,i). hidden + keyemb gather (ballot-rank pack).
__global__ __launch_bounds__(256) void k_pack_gather(
    const float* __restrict__ seq,
    const float* __restrict__ W_key,
    const int* __restrict__ valid,
    const int* __restrict__ kvidx,
    const int* __restrict__ aspect,
    float* __restrict__ hidden,
    float* __restrict__ keyemb) {
  int bq = blockIdx.x;
  int b = bq >> 7;
  int i = bq & (SL - 1);
  int tid = threadIdx.x;
  int lane = tid & 63, wv = tid >> 6;

  __shared__ int s_wcnt[4];
  __shared__ int s_src;

  int v = (tid < SL) ? (valid[b * SL + tid] != 0) : 0;
  unsigned long long m = __ballot(v);
  if (lane == 0) s_wcnt[wv] = __popcll(m);
  if (tid == 0) s_src = SL;  // sentinel
  __syncthreads();
  int count = s_wcnt[0] + s_wcnt[1];
  if (v) {
    int rank = __popcll(m & ((1ull << lane) - 1ull)) + (wv == 1 ? s_wcnt[0] : 0);
    if (rank == i) s_src = tid;
  }
  __syncthreads();
  int src = s_src;

  if (tid < HD / 4) {  // 192 threads, one float4 each
    float4 hv = make_float4(0.f, 0.f, 0.f, 0.f);
    if (i < count && src < SL) {
      float asp = (float)aspect[b * SL + i];
      const float4* srow = (const float4*)(seq + ((size_t)(b * SL + src)) * HD);
      float4 s = srow[tid];
      hv = make_float4(s.x * asp, s.y * asp, s.z * asp, s.w * asp);
    }
    ((float4*)(hidden + (size_t)bq * HD))[tid] = hv;

    int id = kvidx[b * SL + i];
    float4 kv = make_float4(0.f, 0.f, 0.f, 0.f);
    if (id != 0) {
      kv = ((const float4*)(W_key + (size_t)id * HD))[tid];
    }
    ((float4*)(keyemb + (size_t)bq * HD))[tid] = kv;
  }
}

// Kernel 2: u[b,q,k] = (hidden[b,q,:] . keyemb[b,k,:]) / sqrt(H)
// Tiled GEMM: block = (b, 16-q tile, 32-k tile); reads each panel once.
__global__ __launch_bounds__(256) void k_score(
    const float* __restrict__ hidden,
    const float* __restrict__ keyemb,
    float* __restrict__ u) {
  int blk = blockIdx.x;
  int b = blk >> 5;
  int qt = (blk >> 2) & 7;
  int kt = blk & 3;
  int q0 = qt * 16, k0 = kt * 32;
  int tid = threadIdx.x;
  int q = tid & 15, k2 = tid >> 4;  // outputs (q0+q, k0+2k2), (q0+q, k0+2k2+1)

  __shared__ __align__(16) float sA[16][132];  // pad 132: breaks bank aliasing
  __shared__ __align__(16) float sB[32][132];

  float acc0 = 0.f, acc1 = 0.f;
  for (int c = 0; c < 6; ++c) {
    int h0 = c * 128;
    {  // stage A: 16 rows x 128
      int r = tid >> 4, hq = tid & 15;
      const float4* src = (const float4*)(hidden + ((size_t)(b * SL + q0 + r)) * HD + h0);
      *(float4*)&sA[r][hq * 4] = src[hq];
      *(float4*)&sA[r][64 + hq * 4] = src[hq + 16];
    }
    {  // stage B: 32 rows x 128
      int r = tid >> 3, hq = tid & 7;
      const float4* src = (const float4*)(keyemb + ((size_t)(b * SL + k0 + r)) * HD + h0);
      *(float4*)&sB[r][hq * 4] = src[hq];
      *(float4*)&sB[r][32 + hq * 4] = src[hq + 8];
      *(float4*)&sB[r][64 + hq * 4] = src[hq + 16];
      *(float4*)&sB[r][96 + hq * 4] = src[hq + 24];
    }
    __syncthreads();
#pragma unroll
    for (int hh = 0; hh < 128; hh += 4) {
      float4 a = *(const float4*)&sA[q][hh];
      float4 x = *(const float4*)&sB[2 * k2][hh];
      float4 y = *(const float4*)&sB[2 * k2 + 1][hh];
      acc0 += a.x * x.x + a.y * x.y + a.z * x.z + a.w * x.w;
      acc1 += a.x * y.x + a.y * y.y + a.z * y.z + a.w * y.w;
    }
    __syncthreads();
  }
  const float rscale = 0.03608439182435161f;  // 1/sqrt(768)
  float* urow = u + ((size_t)(b * SL + q0 + q)) * SL + k0;
  urow[2 * k2] = acc0 * rscale;
  urow[2 * k2 + 1] = acc1 * rscale;
}

// Kernel 3: per (b,q): softmax over pos-mask, compact, 8-wave value gather.
__global__ __launch_bounds__(512) void k_attend(
    const float* __restrict__ u,
    const int* __restrict__ features,
    const int* __restrict__ pos,
    const float* __restrict__ W_val,
    float* __restrict__ o) {
  int bq = blockIdx.x;
  int tid = threadIdx.x;
  int wave = tid >> 6, lane = tid & 63;

  __shared__ float s_p[SL];
  __shared__ int s_f[SL];
  __shared__ float s_pc[SL];
  __shared__ int s_fc[SL];
  __shared__ float s_o[8][HD];
  __shared__ float s_sum;
  __shared__ int s_cnt2[2];
  __shared__ int s_m;

  if (tid < SL) {
    s_f[tid] = features[(size_t)bq * SL + tid];
    float d = (pos[(size_t)bq * SL + tid] != 0) ? expf(u[(size_t)bq * SL + tid]) : 0.f;
    s_p[tid] = d;
  }
  __syncthreads();
  if (tid < 64) {  // wave 0 tree-reduces the denominator
    float part = s_p[tid] + s_p[tid + 64];
#pragma unroll
    for (int off = 32; off; off >>= 1) part += __shfl_xor(part, off);
    if (tid == 0) s_sum = part + 1e-10f;
  }
  __syncthreads();

  // compact surviving (p, f) pairs
  int keep = 0;
  float pv = 0.f;
  int fv = 0;
  if (tid < SL) {
    pv = s_p[tid] / s_sum;
    fv = s_f[tid];
    keep = (pv != 0.f) && (fv != 0);
  }
  unsigned long long km = __ballot(keep);
  if (lane == 0 && wave < 2) s_cnt2[wave] = __popcll(km);
  __syncthreads();
  if (keep) {
    int rank = __popcll(km & ((1ull << lane) - 1ull)) + (wave == 1 ? s_cnt2[0] : 0);
    s_pc[rank] = pv;
    s_fc[rank] = fv;
  }
  if (tid == 0) s_m = s_cnt2[0] + s_cnt2[1];
  __syncthreads();
  int mm = s_m;

  // each of 8 waves accumulates a full 768-wide partial over its k-slice
  float4 a0 = make_float4(0.f, 0.f, 0.f, 0.f);
  float4 a1 = a0, a2 = a0;
  for (int e = wave; e < mm; e += 8) {
    float pk = s_pc[e];
    const float4* vr4 = (const float4*)(W_val + (size_t)s_fc[e] * HD);
    float4 v0 = vr4[lane];
    float4 v1 = vr4[lane + 64];
    float4 v2 = vr4[lane + 128];
    a0.x += pk * v0.x; a0.y += pk * v0.y; a0.z += pk * v0.z; a0.w += pk * v0.w;
    a1.x += pk * v1.x; a1.y += pk * v1.y; a1.z += pk * v1.z; a1.w += pk * v1.w;
    a2.x += pk * v2.x; a2.y += pk * v2.y; a2.z += pk * v2.z; a2.w += pk * v2.w;
  }
  ((float4*)s_o[wave])[lane] = a0;
  ((float4*)s_o[wave])[lane + 64] = a1;
  ((float4*)s_o[wave])[lane + 128] = a2;
  __syncthreads();

  float* orow = o + (size_t)bq * HD;
  for (int h = tid; h < HD; h += 512) {
    float s = 0.f;
#pragma unroll
    for (int w = 0; w < 8; ++w) s += s_o[w][h];
    orow[h] = s;
  }
}

// Kernel 4: column mean with !=0 count. grid (NB*6), each block 128 columns.
__global__ __launch_bounds__(256) void k_avg(
    const float* __restrict__ o, float* __restrict__ avg) {
  int b = blockIdx.x / 6, c = blockIdx.x % 6;
  int tid = threadIdx.x;
  int hc = tid & 127;
  int h = c * 128 + hc;
  int slice = tid >> 7;
  __shared__ float s_sum[2][128];
  __shared__ int s_cnt[2][128];
  float sum = 0.f;
  int cnt = 0;
#pragma unroll 8
  for (int q = slice * 64; q < (slice + 1) * 64; ++q) {
    float v = o[((size_t)(b * SL + q)) * HD + h];
    sum += v;
    cnt += (v != 0.f) ? 1 : 0;
  }
  s_sum[slice][hc] = sum;
  s_cnt[slice][hc] = cnt;
  __syncthreads();
  if (tid < 128) {
    float t = s_sum[0][tid] + s_sum[1][tid];
    int cc = s_cnt[0][tid] + s_cnt[1][tid];
    avg[(size_t)b * HD + c * 128 + tid] = t / (float)cc;
  }
}

// Kernel 5: logits = [pooled, avg] @ W_dense^T + b_dense
__global__ __launch_bounds__(192) void k_dense(
    const float* __restrict__ pooled,
    const float* __restrict__ avg,
    const float* __restrict__ W_dense,
    const float* __restrict__ b_dense,
    float* __restrict__ out) {
  int b = blockIdx.x;
  int tid = threadIdx.x;
  int n = tid >> 6, lane = tid & 63;
  float part = 0.f;
  for (int j = lane; j < HD; j += 64)
    part += pooled[(size_t)b * HD + j] * W_dense[(size_t)n * (2 * HD) + j];
  for (int j = lane; j < HD; j += 64)
    part += avg[(size_t)b * HD + j] * W_dense[(size_t)n * (2 * HD) + HD + j];
#pragma unroll
  for (int off = 32; off; off >>= 1) part += __shfl_xor(part, off);
  if (lane == 0) out[b * 3 + n] = part + b_dense[n];
}

extern "C" void kernel_launch(void* const* d_in, const int* in_sizes, int n_in,
                              void* d_out, int out_size, void* d_ws, size_t ws_size,
                              hipStream_t stream) {
  const float* seq     = (const float*)d_in[0];
  const float* pooled  = (const float*)d_in[1];
  const float* W_key   = (const float*)d_in[2];
  const float* W_val   = (const float*)d_in[3];
  const float* W_dense = (const float*)d_in[4];
  const float* b_dense = (const float*)d_in[5];
  const int* valid     = (const int*)d_in[6];
  const int* kvidx     = (const int*)d_in[7];
  const int* features  = (const int*)d_in[8];
  const int* pos       = (const int*)d_in[9];
  const int* aspect    = (const int*)d_in[10];
  float* out = (float*)d_out;

  float* hidden = (float*)d_ws;                       // [B,L,H]
  float* keyemb = hidden + (size_t)NB * SL * HD;      // [B,L,H]
  float* o      = keyemb + (size_t)NB * SL * HD;      // [B,L,H]
  float* avg    = o + (size_t)NB * SL * HD;           // [B,H]
  float* u      = avg + (size_t)NB * HD;              // [B,L,L]

  k_pack_gather<<<NB * SL, 256, 0, stream>>>(seq, W_key, valid, kvidx, aspect, hidden, keyemb);
  k_score<<<NB * 32, 256, 0, stream>>>(hidden, keyemb, u);
  k_attend<<<NB * SL, 512, 0, stream>>>(u, features, pos, W_val, o);
  k_avg<<<NB * 6, 256, 0, stream>>>(o, avg);
  k_dense<<<NB, 192, 0, stream>>>(pooled, avg, W_dense, b_dense, out);
}

// Round 5
// 65.094 us; speedup vs baseline: 1.1729x; 1.1729x over previous
//
#include <hip/hip_runtime.h>

#define NB 8
#define SL 128
#define HD 768

// Kernel 1: one block per (b,i). hidden + keyemb gather (ballot-rank pack).
// Block index swizzled so batch b pins to XCD b (blockIdx % 8 == b).
__global__ __launch_bounds__(256) void k_pack_gather(
    const float* __restrict__ seq,
    const float* __restrict__ W_key,
    const int* __restrict__ valid,
    const int* __restrict__ kvidx,
    const int* __restrict__ aspect,
    float* __restrict__ hidden,
    float* __restrict__ keyemb) {
  int blk = blockIdx.x;
  int b = blk & 7;
  int i = blk >> 3;
  int bq = b * SL + i;
  int tid = threadIdx.x;
  int lane = tid & 63, wv = tid >> 6;

  __shared__ int s_wcnt[4];
  __shared__ int s_src;

  int v = (tid < SL) ? (valid[b * SL + tid] != 0) : 0;
  unsigned long long m = __ballot(v);
  if (lane == 0) s_wcnt[wv] = __popcll(m);
  if (tid == 0) s_src = SL;  // sentinel
  __syncthreads();
  int count = s_wcnt[0] + s_wcnt[1];
  if (v) {
    int rank = __popcll(m & ((1ull << lane) - 1ull)) + (wv == 1 ? s_wcnt[0] : 0);
    if (rank == i) s_src = tid;
  }
  __syncthreads();
  int src = s_src;

  if (tid < HD / 4) {  // 192 threads, one float4 each
    float4 hv = make_float4(0.f, 0.f, 0.f, 0.f);
    if (i < count && src < SL) {
      float asp = (float)aspect[b * SL + i];
      const float4* srow = (const float4*)(seq + ((size_t)(b * SL + src)) * HD);
      float4 s = srow[tid];
      hv = make_float4(s.x * asp, s.y * asp, s.z * asp, s.w * asp);
    }
    ((float4*)(hidden + (size_t)bq * HD))[tid] = hv;

    int id = kvidx[b * SL + i];
    float4 kv = make_float4(0.f, 0.f, 0.f, 0.f);
    if (id != 0) {
      kv = ((const float4*)(W_key + (size_t)id * HD))[tid];
    }
    ((float4*)(keyemb + (size_t)bq * HD))[tid] = kv;
  }
}

// Kernel 2 (fused): per (b,q) block, 512 threads / 8 waves.
// QK dot -> masked softmax -> compacted, register-pipelined value gather.
// Block index swizzled so batch b pins to XCD b: keyemb panel stays L2-local.
__global__ __launch_bounds__(512) void k_attend(
    const float* __restrict__ hidden,
    const float* __restrict__ keyemb,
    const int* __restrict__ features,
    const int* __restrict__ pos,
    const float* __restrict__ W_val,
    float* __restrict__ o) {
  int blk = blockIdx.x;
  int b = blk & 7;
  int q = blk >> 3;
  int bq = b * SL + q;
  int tid = threadIdx.x;
  int wave = tid >> 6, lane = tid & 63;

  __shared__ float4 s_h4[HD / 4];
  __shared__ float s_p[SL];
  __shared__ int s_f[SL];
  __shared__ float s_pc[SL];
  __shared__ int s_fc[SL];
  __shared__ float s_o[8][HD];
  __shared__ float s_sum;
  __shared__ int s_cnt2[2];
  __shared__ int s_m;

  if (tid < HD / 4) s_h4[tid] = ((const float4*)(hidden + (size_t)bq * HD))[tid];
  if (tid < SL) s_f[tid] = features[(size_t)bq * SL + tid];
  __syncthreads();

  const float rscale = 0.03608439182435161f;  // 1/sqrt(768)
  for (int k = wave; k < SL; k += 8) {
    const float4* kr4 = (const float4*)(keyemb + ((size_t)(b * SL + k)) * HD);
    float part = 0.f;
#pragma unroll
    for (int j = 0; j < 3; ++j) {
      float4 a = kr4[lane + 64 * j];
      float4 h = s_h4[lane + 64 * j];
      part += a.x * h.x + a.y * h.y + a.z * h.z + a.w * h.w;
    }
#pragma unroll
    for (int off = 32; off; off >>= 1) part += __shfl_xor(part, off);
    if (lane == 0) s_p[k] = part * rscale;
  }
  __syncthreads();
  if (tid < SL) {
    float d = (pos[(size_t)bq * SL + tid] != 0) ? expf(s_p[tid]) : 0.f;
    s_p[tid] = d;
  }
  __syncthreads();
  if (tid < 64) {  // wave 0 tree-reduces the denominator
    float part = s_p[tid] + s_p[tid + 64];
#pragma unroll
    for (int off = 32; off; off >>= 1) part += __shfl_xor(part, off);
    if (tid == 0) s_sum = part + 1e-10f;
  }
  __syncthreads();

  // compact surviving (p, f) pairs
  int keep = 0;
  float pv = 0.f;
  int fv = 0;
  if (tid < SL) {
    pv = s_p[tid] / s_sum;
    fv = s_f[tid];
    keep = (pv != 0.f) && (fv != 0);
  }
  unsigned long long km = __ballot(keep);
  if (lane == 0 && wave < 2) s_cnt2[wave] = __popcll(km);
  __syncthreads();
  if (keep) {
    int rank = __popcll(km & ((1ull << lane) - 1ull)) + (wave == 1 ? s_cnt2[0] : 0);
    s_pc[rank] = pv;
    s_fc[rank] = fv;
  }
  if (tid == 0) s_m = s_cnt2[0] + s_cnt2[1];
  __syncthreads();
  int mm = s_m;

  // Gather: wave w owns entries e = w + 8*l. Entry (p,f) prefetched to lane
  // registers, broadcast by shfl; 2-deep pipeline keeps next row's loads in
  // flight during current row's FMAs. No LDS in the loop-carried chain.
  int niter = (mm > wave) ? ((mm - wave + 7) >> 3) : 0;
  float myp = 0.f;
  int myf = 0;
  {
    int el = wave + 8 * lane;
    if (lane < 16 && el < mm) { myp = s_pc[el]; myf = s_fc[el]; }
  }
  float4 a0 = make_float4(0.f, 0.f, 0.f, 0.f);
  float4 a1 = a0, a2 = a0;
  float4 v0, v1, v2;
  float pk = 0.f;
  if (niter > 0) {
    pk = __shfl(myp, 0);
    int f = __shfl(myf, 0);
    const float4* vr = (const float4*)(W_val + (size_t)f * HD);
    v0 = vr[lane]; v1 = vr[lane + 64]; v2 = vr[lane + 128];
  }
  for (int j = 1; j < niter; ++j) {
    float pkn = __shfl(myp, j);
    int f = __shfl(myf, j);
    const float4* vr = (const float4*)(W_val + (size_t)f * HD);
    float4 n0 = vr[lane], n1 = vr[lane + 64], n2 = vr[lane + 128];
    a0.x += pk * v0.x; a0.y += pk * v0.y; a0.z += pk * v0.z; a0.w += pk * v0.w;
    a1.x += pk * v1.x; a1.y += pk * v1.y; a1.z += pk * v1.z; a1.w += pk * v1.w;
    a2.x += pk * v2.x; a2.y += pk * v2.y; a2.z += pk * v2.z; a2.w += pk * v2.w;
    v0 = n0; v1 = n1; v2 = n2; pk = pkn;
  }
  if (niter > 0) {
    a0.x += pk * v0.x; a0.y += pk * v0.y; a0.z += pk * v0.z; a0.w += pk * v0.w;
    a1.x += pk * v1.x; a1.y += pk * v1.y; a1.z += pk * v1.z; a1.w += pk * v1.w;
    a2.x += pk * v2.x; a2.y += pk * v2.y; a2.z += pk * v2.z; a2.w += pk * v2.w;
  }
  ((float4*)s_o[wave])[lane] = a0;
  ((float4*)s_o[wave])[lane + 64] = a1;
  ((float4*)s_o[wave])[lane + 128] = a2;
  __syncthreads();

  float* orow = o + (size_t)bq * HD;
  for (int h = tid; h < HD; h += 512) {
    float s = 0.f;
#pragma unroll
    for (int w = 0; w < 8; ++w) s += s_o[w][h];
    orow[h] = s;
  }
}

// Kernel 3: column mean with !=0 count. grid (NB*6), each block 128 columns.
__global__ __launch_bounds__(256) void k_avg(
    const float* __restrict__ o, float* __restrict__ avg) {
  int b = blockIdx.x / 6, c = blockIdx.x % 6;
  int tid = threadIdx.x;
  int hc = tid & 127;
  int h = c * 128 + hc;
  int slice = tid >> 7;
  __shared__ float s_sum[2][128];
  __shared__ int s_cnt[2][128];
  float sum = 0.f;
  int cnt = 0;
#pragma unroll 8
  for (int q = slice * 64; q < (slice + 1) * 64; ++q) {
    float v = o[((size_t)(b * SL + q)) * HD + h];
    sum += v;
    cnt += (v != 0.f) ? 1 : 0;
  }
  s_sum[slice][hc] = sum;
  s_cnt[slice][hc] = cnt;
  __syncthreads();
  if (tid < 128) {
    float t = s_sum[0][tid] + s_sum[1][tid];
    int cc = s_cnt[0][tid] + s_cnt[1][tid];
    avg[(size_t)b * HD + c * 128 + tid] = t / (float)cc;  // IEEE inf/nan if cc==0
  }
}

// Kernel 4: logits = [pooled, avg] @ W_dense^T + b_dense
__global__ __launch_bounds__(192) void k_dense(
    const float* __restrict__ pooled,
    const float* __restrict__ avg,
    const float* __restrict__ W_dense,
    const float* __restrict__ b_dense,
    float* __restrict__ out) {
  int b = blockIdx.x;
  int tid = threadIdx.x;
  int n = tid >> 6, lane = tid & 63;
  float part = 0.f;
  for (int j = lane; j < HD; j += 64)
    part += pooled[(size_t)b * HD + j] * W_dense[(size_t)n * (2 * HD) + j];
  for (int j = lane; j < HD; j += 64)
    part += avg[(size_t)b * HD + j] * W_dense[(size_t)n * (2 * HD) + HD + j];
#pragma unroll
  for (int off = 32; off; off >>= 1) part += __shfl_xor(part, off);
  if (lane == 0) out[b * 3 + n] = part + b_dense[n];
}

extern "C" void kernel_launch(void* const* d_in, const int* in_sizes, int n_in,
                              void* d_out, int out_size, void* d_ws, size_t ws_size,
                              hipStream_t stream) {
  const float* seq     = (const float*)d_in[0];
  const float* pooled  = (const float*)d_in[1];
  const float* W_key   = (const float*)d_in[2];
  const float* W_val   = (const float*)d_in[3];
  const float* W_dense = (const float*)d_in[4];
  const float* b_dense = (const float*)d_in[5];
  const int* valid     = (const int*)d_in[6];
  const int* kvidx     = (const int*)d_in[7];
  const int* features  = (const int*)d_in[8];
  const int* pos       = (const int*)d_in[9];
  const int* aspect    = (const int*)d_in[10];
  float* out = (float*)d_out;

  float* hidden = (float*)d_ws;                       // [B,L,H]
  float* keyemb = hidden + (size_t)NB * SL * HD;      // [B,L,H]
  float* o      = keyemb + (size_t)NB * SL * HD;      // [B,L,H]
  float* avg    = o + (size_t)NB * SL * HD;           // [B,H]

  k_pack_gather<<<NB * SL, 256, 0, stream>>>(seq, W_key, valid, kvidx, aspect, hidden, keyemb);
  k_attend<<<NB * SL, 512, 0, stream>>>(hidden, keyemb, features, pos, W_val, o);
  k_avg<<<NB * 6, 256, 0, stream>>>(o, avg);
  k_dense<<<NB, 192, 0, stream>>>(pooled, avg, W_dense, b_dense, out);
}